// Round 5
// baseline (139.824 us; speedup 1.0000x reference)
//
#include <hip/hip_runtime.h>

#define N_NODES 50000
#define D 128
#define SCAN_NBLK 49   // ceil(50000/1024)
#define AGG_LDA 136    // bf16 units per aggT row (128 data + 8 pad) -> 272B stride

typedef short bf16x8 __attribute__((ext_vector_type(8)));
typedef float f32x4 __attribute__((ext_vector_type(4)));

__device__ __forceinline__ ushort f2bf(float f) {
    uint u = __float_as_uint(f);
    u += 0x7FFF + ((u >> 16) & 1);     // round-to-nearest-even
    return (ushort)(u >> 16);
}

// unpack 8 bf16 (int4) and accumulate into a[0..8)
__device__ __forceinline__ void addrow(int4 q, float* a) {
    a[0] += __uint_as_float((uint)q.x << 16);
    a[1] += __uint_as_float((uint)q.x & 0xFFFF0000u);
    a[2] += __uint_as_float((uint)q.y << 16);
    a[3] += __uint_as_float((uint)q.y & 0xFFFF0000u);
    a[4] += __uint_as_float((uint)q.z << 16);
    a[5] += __uint_as_float((uint)q.z & 0xFFFF0000u);
    a[6] += __uint_as_float((uint)q.w << 16);
    a[7] += __uint_as_float((uint)q.w & 0xFFFF0000u);
}

// ================= prep: zero deg + x->bf16 + W transpose->bf16 =============
__global__ __launch_bounds__(256) void prep_kernel(const float* __restrict__ x,
                                                   const float* __restrict__ Wl,
                                                   const float* __restrict__ Wr,
                                                   int* __restrict__ deg,
                                                   ushort* __restrict__ x_bf,
                                                   ushort* __restrict__ Bt) {
    int i = blockIdx.x * 256 + threadIdx.x;
    if (i < (N_NODES * D) / 4) {
        float4 v = ((const float4*)x)[i];
        ushort4 o;
        o.x = f2bf(v.x); o.y = f2bf(v.y); o.z = f2bf(v.z); o.w = f2bf(v.w);
        ((ushort4*)x_bf)[i] = o;
    }
    if (i < 50016) deg[i] = 0;
    if (i < 2 * D * D) {
        int w = i >> 14;
        int k = (i >> 7) & 127;
        int n = i & 127;
        const float* W = w ? Wr : Wl;
        Bt[w * D * D + n * D + k] = f2bf(W[k * D + n]);
    }
}

// ---------------- histogram + per-edge rank (ushort) ----------------
__global__ void hist_rank_kernel(const int* __restrict__ dst, int* __restrict__ deg,
                                 ushort* __restrict__ rank, int E) {
    int e = blockIdx.x * 256 + threadIdx.x;
    if (e < E) rank[e] = (ushort)atomicAdd(&deg[dst[e]], 1);
}

// ---------------- scan A: per-1024-chunk local exclusive scan ---------------
__global__ __launch_bounds__(256) void scanA_kernel(const int* __restrict__ deg,
                                                    int* __restrict__ offsets,
                                                    int* __restrict__ blocksums) {
    __shared__ int wsums[4];
    __shared__ int wbase[4];
    const int t = threadIdx.x;
    const int lane = t & 63;
    const int wid = t >> 6;
    const int base = blockIdx.x * 1024 + t * 4;

    int v0 = 0, v1 = 0, v2 = 0, v3 = 0;
    if (base + 3 < N_NODES) {
        int4 q = *(const int4*)&deg[base];
        v0 = q.x; v1 = q.y; v2 = q.z; v3 = q.w;
    } else {
        if (base + 0 < N_NODES) v0 = deg[base + 0];
        if (base + 1 < N_NODES) v1 = deg[base + 1];
        if (base + 2 < N_NODES) v2 = deg[base + 2];
        if (base + 3 < N_NODES) v3 = deg[base + 3];
    }
    int tsum = v0 + v1 + v2 + v3;

    int sc = tsum;
    #pragma unroll
    for (int off = 1; off < 64; off <<= 1) {
        int u = __shfl_up(sc, off);
        if (lane >= off) sc += u;
    }
    if (lane == 63) wsums[wid] = sc;
    __syncthreads();
    if (t == 0) {
        int c = 0;
        #pragma unroll
        for (int w = 0; w < 4; ++w) { wbase[w] = c; c += wsums[w]; }
    }
    __syncthreads();

    int excl = wbase[wid] + sc - tsum;
    int o0 = excl, o1 = o0 + v0, o2 = o1 + v1, o3 = o2 + v2;
    if (base + 3 < N_NODES) {
        *(int4*)&offsets[base] = make_int4(o0, o1, o2, o3);
    } else {
        if (base + 0 < N_NODES) offsets[base + 0] = o0;
        if (base + 1 < N_NODES) offsets[base + 1] = o1;
        if (base + 2 < N_NODES) offsets[base + 2] = o2;
        if (base + 3 < N_NODES) offsets[base + 3] = o3;
    }
    if (t == 255) blocksums[blockIdx.x] = excl + tsum;
}

// ---------------- scan BC: add block prefix (each block recomputes it) ------
__global__ __launch_bounds__(256) void scanBC_kernel(int* __restrict__ offsets,
                                                     const int* __restrict__ blocksums,
                                                     int E) {
    __shared__ int sbase;
    const int t = threadIdx.x;
    const int b = blockIdx.x;
    if (t < 64) {
        int v = (t < b) ? blocksums[t] : 0;   // sum of preceding blocks
        #pragma unroll
        for (int off = 32; off > 0; off >>= 1) v += __shfl_down(v, off);
        if (t == 0) sbase = v;
    }
    __syncthreads();
    const int add = sbase;
    int base = b * 1024 + t * 4;
    if (base + 3 < N_NODES) {
        int4 q = *(int4*)&offsets[base];
        q.x += add; q.y += add; q.z += add; q.w += add;
        *(int4*)&offsets[base] = q;
    } else {
        if (base + 0 < N_NODES) offsets[base + 0] += add;
        if (base + 1 < N_NODES) offsets[base + 1] += add;
        if (base + 2 < N_NODES) offsets[base + 2] += add;
    }
    if (b == SCAN_NBLK - 1 && t == 0) offsets[N_NODES] = E;
}

// ---------------- scatter edges into CSR order (no atomics, ushort) --------
__global__ void scatter_kernel(const int* __restrict__ src, const int* __restrict__ dst,
                               const int* __restrict__ offsets, const ushort* __restrict__ rank,
                               ushort* __restrict__ sorted_src, int E) {
    int e = blockIdx.x * 256 + threadIdx.x;
    if (e < E) {
        int d = dst[e];
        sorted_src[offsets[d] + (int)rank[e]] = (ushort)src[e];
    }
}

// ======== fused aggregate + dual GEMM + bias + relu =========================
// block = 128 nodes, 256 threads.
// phase 1: mean-aggregate neighbors (bf16 gather, f32 accum) -> aggT in LDS (bf16)
// phase 2: out = relu([aggT | x] @ [Wl;Wr] + b) via 16x16x32 bf16 MFMA,
//          A(x-half) and B fragments read directly from global (L2/L3-hot).
__global__ __launch_bounds__(256) void aggemm_kernel(const ushort* __restrict__ x_bf,
                                                     const ushort* __restrict__ sorted_src,
                                                     const int* __restrict__ offsets,
                                                     const ushort* __restrict__ Bt,
                                                     const float* __restrict__ bias,
                                                     float* __restrict__ out) {
    __shared__ ushort aggT[128 * AGG_LDA];

    const int t = threadIdx.x;
    const int n0 = blockIdx.x * 128;

    // ---------------- phase 1: aggregation ----------------
    {
        const int g = t >> 4;          // node group 0..15
        const int j = t & 15;          // feature chunk: elems j*8 .. j*8+7
        #pragma unroll
        for (int i = 0; i < 8; ++i) {
            const int nl = g * 8 + i;        // local row 0..127
            const int node = n0 + nl;
            float a[8] = {0.f, 0.f, 0.f, 0.f, 0.f, 0.f, 0.f, 0.f};
            if (node < N_NODES) {
                const int s = offsets[node];
                const int e = offsets[node + 1];
                int p = s;
                for (; p + 4 <= e; p += 4) {
                    int s0 = sorted_src[p + 0];
                    int s1 = sorted_src[p + 1];
                    int s2 = sorted_src[p + 2];
                    int s3 = sorted_src[p + 3];
                    int4 q0 = *(const int4*)&x_bf[s0 * D + j * 8];
                    int4 q1 = *(const int4*)&x_bf[s1 * D + j * 8];
                    int4 q2 = *(const int4*)&x_bf[s2 * D + j * 8];
                    int4 q3 = *(const int4*)&x_bf[s3 * D + j * 8];
                    addrow(q0, a); addrow(q1, a); addrow(q2, a); addrow(q3, a);
                }
                for (; p < e; ++p) {
                    int s0 = sorted_src[p];
                    int4 q0 = *(const int4*)&x_bf[s0 * D + j * 8];
                    addrow(q0, a);
                }
                const int dcnt = e - s;
                const float scale = (dcnt > 0) ? (1.0f / (float)dcnt) : 0.0f;
                #pragma unroll
                for (int k = 0; k < 8; ++k) a[k] *= scale;
            }
            ushort tmp[8];
            #pragma unroll
            for (int k = 0; k < 8; ++k) tmp[k] = f2bf(a[k]);
            *(int4*)&aggT[nl * AGG_LDA + j * 8] = *(int4*)tmp;
        }
    }
    __syncthreads();

    // ---------------- phase 2: MFMA GEMM ----------------
    const int w = t >> 6;         // wave 0..3
    const int l = t & 63;
    const int lr = l & 15;        // A row / B col within fragment
    const int kb = l >> 4;        // k-block 0..3

    f32x4 acc[2][8] = {};
    const int rowA0 = w * 32 + lr;
    const int rowA1 = w * 32 + 16 + lr;
    int gr0 = n0 + rowA0; if (gr0 >= N_NODES) gr0 = N_NODES - 1;
    int gr1 = n0 + rowA1; if (gr1 >= N_NODES) gr1 = N_NODES - 1;

    #pragma unroll
    for (int ks = 0; ks < 8; ++ks) {
        bf16x8 af0, af1;
        if (ks < 4) {
            af0 = *(bf16x8*)&aggT[rowA0 * AGG_LDA + ks * 32 + kb * 8];
            af1 = *(bf16x8*)&aggT[rowA1 * AGG_LDA + ks * 32 + kb * 8];
        } else {
            af0 = *(const bf16x8*)&x_bf[gr0 * D + (ks - 4) * 32 + kb * 8];
            af1 = *(const bf16x8*)&x_bf[gr1 * D + (ks - 4) * 32 + kb * 8];
        }
        const ushort* Bbase = Bt + (ks >> 2) * D * D + (ks & 3) * 32 + kb * 8;
        #pragma unroll
        for (int nf = 0; nf < 8; ++nf) {
            bf16x8 bfr = *(const bf16x8*)&Bbase[(nf * 16 + lr) * D];
            acc[0][nf] = __builtin_amdgcn_mfma_f32_16x16x32_bf16(af0, bfr, acc[0][nf], 0, 0, 0);
            acc[1][nf] = __builtin_amdgcn_mfma_f32_16x16x32_bf16(af1, bfr, acc[1][nf], 0, 0, 0);
        }
    }

    // epilogue: C/D layout col = lane&15, row = (lane>>4)*4 + i
    #pragma unroll
    for (int nf = 0; nf < 8; ++nf) {
        const int col = nf * 16 + lr;
        const float bb = bias[col];
        #pragma unroll
        for (int mf = 0; mf < 2; ++mf) {
            #pragma unroll
            for (int i = 0; i < 4; ++i) {
                int row = n0 + w * 32 + mf * 16 + kb * 4 + i;
                if (row < N_NODES)
                    out[row * D + col] = fmaxf(acc[mf][nf][i] + bb, 0.0f);
            }
        }
    }
}

// ============================================================================
extern "C" void kernel_launch(void* const* d_in, const int* in_sizes, int n_in,
                              void* d_out, int out_size, void* d_ws, size_t ws_size,
                              hipStream_t stream) {
    const float* x  = (const float*)d_in[0];
    const int*   ei = (const int*)d_in[1];
    const float* Wl = (const float*)d_in[2];
    const float* Wr = (const float*)d_in[3];
    const float* b  = (const float*)d_in[4];
    float* out = (float*)d_out;

    const int E = in_sizes[1] / 2;
    const int* src = ei;
    const int* dst = ei + E;

    // workspace layout (16B-aligned sections)
    char* wsp = (char*)d_ws;
    int*    deg       = (int*)(wsp + 0);               // 50016 ints
    int*    offsets   = (int*)(wsp + 200064);          // 50032 ints (uses 50001)
    int*    blocksums = (int*)(wsp + 400192);          // 64 ints
    ushort* rank      = (ushort*)(wsp + 400448);       // 800000 ushorts
    ushort* sorted    = (ushort*)(wsp + 2000448);      // 800016 ushorts
    ushort* x_bf      = (ushort*)(wsp + 3600480);      // 6,400,000 ushorts
    ushort* Bt        = (ushort*)(wsp + 16400480);     // 32768 ushorts
    // total = 16,466,016 bytes

    prep_kernel<<<(N_NODES * D / 4 + 255) / 256, 256, 0, stream>>>(x, Wl, Wr, deg, x_bf, Bt);
    hist_rank_kernel<<<(E + 255) / 256, 256, 0, stream>>>(dst, deg, rank, E);
    scanA_kernel<<<SCAN_NBLK, 256, 0, stream>>>(deg, offsets, blocksums);
    scanBC_kernel<<<SCAN_NBLK, 256, 0, stream>>>(offsets, blocksums, E);
    scatter_kernel<<<(E + 255) / 256, 256, 0, stream>>>(src, dst, offsets, rank, sorted, E);
    aggemm_kernel<<<(N_NODES + 127) / 128, 256, 0, stream>>>(x_bf, sorted, offsets, Bt, b, out);
}

// Round 6
// 119.417 us; speedup vs baseline: 1.1709x; 1.1709x over previous
//
#include <hip/hip_runtime.h>

#define N_NODES 50000
#define D 128
#define SCAN_NBLK 49   // ceil(50000/1024)

typedef short bf16x8 __attribute__((ext_vector_type(8)));
typedef float f32x4 __attribute__((ext_vector_type(4)));

__device__ __forceinline__ ushort f2bf(float f) {
    uint u = __float_as_uint(f);
    u += 0x7FFF + ((u >> 16) & 1);     // round-to-nearest-even
    return (ushort)(u >> 16);
}

// unpack 8 bf16 (int4) and accumulate into a[0..8)
__device__ __forceinline__ void addrow(int4 q, float* a) {
    a[0] += __uint_as_float((uint)q.x << 16);
    a[1] += __uint_as_float((uint)q.x & 0xFFFF0000u);
    a[2] += __uint_as_float((uint)q.y << 16);
    a[3] += __uint_as_float((uint)q.y & 0xFFFF0000u);
    a[4] += __uint_as_float((uint)q.z << 16);
    a[5] += __uint_as_float((uint)q.z & 0xFFFF0000u);
    a[6] += __uint_as_float((uint)q.w << 16);
    a[7] += __uint_as_float((uint)q.w & 0xFFFF0000u);
}

// ====== fused: x->bf16 convert + fragment-major B build + hist/rank ========
// deg must be zeroed beforehand (hipMemsetAsync).
__global__ __launch_bounds__(256) void conv_hist_kernel(const float* __restrict__ x,
                                                        const float* __restrict__ Wl,
                                                        const float* __restrict__ Wr,
                                                        const int* __restrict__ dst,
                                                        int* __restrict__ deg,
                                                        ushort* __restrict__ rank,
                                                        ushort* __restrict__ x_bf,
                                                        ushort* __restrict__ Btf,
                                                        int E) {
    const int i = blockIdx.x * 256 + threadIdx.x;
    // ---- x -> bf16 (1.6M float4) ----
    if (i < (N_NODES * D) / 4) {
        float4 v = ((const float4*)x)[i];
        ushort4 o;
        o.x = f2bf(v.x); o.y = f2bf(v.y); o.z = f2bf(v.z); o.w = f2bf(v.w);
        ((ushort4*)x_bf)[i] = o;
    }
    // ---- fragment-major B: Btf[(ks*8+nf)*64 + l][j] = W[k][col] ----
    // (ks<4 -> W_l with k=(ks&3)*32+kb*8+j ; ks>=4 -> W_r)
    if (i < 32768) {
        int j  = i & 7;
        int l  = (i >> 3) & 63;
        int nf = (i >> 9) & 7;
        int ks = (i >> 12) & 7;
        int lr = l & 15, kb = l >> 4;
        int col  = nf * 16 + lr;
        int kloc = (ks & 3) * 32 + kb * 8 + j;
        const float* W = (ks < 4) ? Wl : Wr;
        Btf[i] = f2bf(W[kloc * D + col]);
    }
    // ---- histogram + per-edge rank ----
    if (i < E) rank[i] = (ushort)atomicAdd(&deg[dst[i]], 1);
}

// ---------------- scan A: per-1024-chunk local exclusive scan ---------------
__global__ __launch_bounds__(256) void scanA_kernel(const int* __restrict__ deg,
                                                    int* __restrict__ offsets,
                                                    int* __restrict__ blocksums) {
    __shared__ int wsums[4];
    __shared__ int wbase[4];
    const int t = threadIdx.x;
    const int lane = t & 63;
    const int wid = t >> 6;
    const int base = blockIdx.x * 1024 + t * 4;

    int v0 = 0, v1 = 0, v2 = 0, v3 = 0;
    if (base + 3 < N_NODES) {
        int4 q = *(const int4*)&deg[base];
        v0 = q.x; v1 = q.y; v2 = q.z; v3 = q.w;
    } else {
        if (base + 0 < N_NODES) v0 = deg[base + 0];
        if (base + 1 < N_NODES) v1 = deg[base + 1];
        if (base + 2 < N_NODES) v2 = deg[base + 2];
        if (base + 3 < N_NODES) v3 = deg[base + 3];
    }
    int tsum = v0 + v1 + v2 + v3;

    int sc = tsum;
    #pragma unroll
    for (int off = 1; off < 64; off <<= 1) {
        int u = __shfl_up(sc, off);
        if (lane >= off) sc += u;
    }
    if (lane == 63) wsums[wid] = sc;
    __syncthreads();
    if (t == 0) {
        int c = 0;
        #pragma unroll
        for (int w = 0; w < 4; ++w) { wbase[w] = c; c += wsums[w]; }
    }
    __syncthreads();

    int excl = wbase[wid] + sc - tsum;
    int o0 = excl, o1 = o0 + v0, o2 = o1 + v1, o3 = o2 + v2;
    if (base + 3 < N_NODES) {
        *(int4*)&offsets[base] = make_int4(o0, o1, o2, o3);
    } else {
        if (base + 0 < N_NODES) offsets[base + 0] = o0;
        if (base + 1 < N_NODES) offsets[base + 1] = o1;
        if (base + 2 < N_NODES) offsets[base + 2] = o2;
        if (base + 3 < N_NODES) offsets[base + 3] = o3;
    }
    if (t == 255) blocksums[blockIdx.x] = excl + tsum;
}

// ---------------- scan BC: add block prefix (each block recomputes it) ------
__global__ __launch_bounds__(256) void scanBC_kernel(int* __restrict__ offsets,
                                                     const int* __restrict__ blocksums,
                                                     int E) {
    __shared__ int sbase;
    const int t = threadIdx.x;
    const int b = blockIdx.x;
    if (t < 64) {
        int v = (t < b) ? blocksums[t] : 0;
        #pragma unroll
        for (int off = 32; off > 0; off >>= 1) v += __shfl_down(v, off);
        if (t == 0) sbase = v;
    }
    __syncthreads();
    const int add = sbase;
    int base = b * 1024 + t * 4;
    if (base + 3 < N_NODES) {
        int4 q = *(int4*)&offsets[base];
        q.x += add; q.y += add; q.z += add; q.w += add;
        *(int4*)&offsets[base] = q;
    } else {
        if (base + 0 < N_NODES) offsets[base + 0] += add;
        if (base + 1 < N_NODES) offsets[base + 1] += add;
        if (base + 2 < N_NODES) offsets[base + 2] += add;
    }
    if (b == SCAN_NBLK - 1 && t == 0) offsets[N_NODES] = E;
}

// ---------------- scatter edges into CSR order (no atomics, ushort) --------
__global__ void scatter_kernel(const int* __restrict__ src, const int* __restrict__ dst,
                               const int* __restrict__ offsets, const ushort* __restrict__ rank,
                               ushort* __restrict__ sorted_src, int E) {
    int e = blockIdx.x * 256 + threadIdx.x;
    if (e < E) {
        int d = dst[e];
        sorted_src[offsets[d] + (int)rank[e]] = (ushort)src[e];
    }
}

// ---------------- per-node mean aggregation -> bf16 output ----------------
// 16 lanes per node (int4 = 8 bf16 each), 16 nodes per 256-thread block
__global__ __launch_bounds__(256) void aggregate_bf(const ushort* __restrict__ x_bf,
                                                    const ushort* __restrict__ sorted_src,
                                                    const int* __restrict__ offsets,
                                                    ushort* __restrict__ agg_bf) {
    const int g = threadIdx.x >> 4;          // node slot 0..15
    const int j = threadIdx.x & 15;          // feature chunk: elems j*8..j*8+7
    const int node = blockIdx.x * 16 + g;
    if (node >= N_NODES) return;
    const int s = offsets[node];
    const int e = offsets[node + 1];

    float a[8] = {0.f, 0.f, 0.f, 0.f, 0.f, 0.f, 0.f, 0.f};
    int p = s;
    for (; p + 4 <= e; p += 4) {
        int s0 = sorted_src[p + 0];
        int s1 = sorted_src[p + 1];
        int s2 = sorted_src[p + 2];
        int s3 = sorted_src[p + 3];
        int4 q0 = *(const int4*)&x_bf[s0 * D + j * 8];
        int4 q1 = *(const int4*)&x_bf[s1 * D + j * 8];
        int4 q2 = *(const int4*)&x_bf[s2 * D + j * 8];
        int4 q3 = *(const int4*)&x_bf[s3 * D + j * 8];
        addrow(q0, a); addrow(q1, a); addrow(q2, a); addrow(q3, a);
    }
    for (; p < e; ++p) {
        int s0 = sorted_src[p];
        int4 q0 = *(const int4*)&x_bf[s0 * D + j * 8];
        addrow(q0, a);
    }
    const int dcnt = e - s;
    const float scale = (dcnt > 0) ? (1.0f / (float)dcnt) : 0.0f;
    ushort tmp[8];
    #pragma unroll
    for (int k = 0; k < 8; ++k) tmp[k] = f2bf(a[k] * scale);
    *(int4*)&agg_bf[node * D + j * 8] = *(int4*)tmp;
}

// ---------------- GEMM, 0 LDS, 0 barriers: out=relu([agg|x]@[Wl;Wr]+b) -----
// 64 rows/block, 4 waves; wave computes 16 rows x 128 cols.
// A fragments direct from global bf16 (L2-hot); B from fragment-major Btf
// (fully coalesced 1KB/instruction loads).
__global__ __launch_bounds__(256) void gemm_direct(const ushort* __restrict__ agg_bf,
                                                   const ushort* __restrict__ x_bf,
                                                   const ushort* __restrict__ Btf,
                                                   const float* __restrict__ bias,
                                                   float* __restrict__ out) {
    const int t = threadIdx.x;
    const int w = t >> 6;
    const int l = t & 63;
    const int lr = l & 15;
    const int kb = l >> 4;
    const int n0 = blockIdx.x * 64;

    int r = n0 + w * 16 + lr;
    if (r >= N_NODES) r = N_NODES - 1;

    f32x4 acc[8] = {};

    #pragma unroll
    for (int ks = 0; ks < 8; ++ks) {
        bf16x8 af = (ks < 4)
            ? *(const bf16x8*)&agg_bf[r * D + ks * 32 + kb * 8]
            : *(const bf16x8*)&x_bf[r * D + (ks - 4) * 32 + kb * 8];
        const ushort* bp = Btf + (size_t)(ks * 8 * 64 + l) * 8;
        #pragma unroll
        for (int nf = 0; nf < 8; ++nf) {
            bf16x8 bfr = *(const bf16x8*)&bp[nf * 64 * 8];
            acc[nf] = __builtin_amdgcn_mfma_f32_16x16x32_bf16(af, bfr, acc[nf], 0, 0, 0);
        }
    }

    // C/D layout: col = lane&15, row = (lane>>4)*4 + i
    #pragma unroll
    for (int nf = 0; nf < 8; ++nf) {
        const int col = nf * 16 + lr;
        const float bb = bias[col];
        #pragma unroll
        for (int i = 0; i < 4; ++i) {
            int row = n0 + w * 16 + kb * 4 + i;
            if (row < N_NODES)
                out[row * D + col] = fmaxf(acc[nf][i] + bb, 0.0f);
        }
    }
}

// ============================================================================
extern "C" void kernel_launch(void* const* d_in, const int* in_sizes, int n_in,
                              void* d_out, int out_size, void* d_ws, size_t ws_size,
                              hipStream_t stream) {
    const float* x  = (const float*)d_in[0];
    const int*   ei = (const int*)d_in[1];
    const float* Wl = (const float*)d_in[2];
    const float* Wr = (const float*)d_in[3];
    const float* b  = (const float*)d_in[4];
    float* out = (float*)d_out;

    const int E = in_sizes[1] / 2;
    const int* src = ei;
    const int* dst = ei + E;

    // workspace layout (16B-aligned sections)
    char* wsp = (char*)d_ws;
    int*    deg       = (int*)(wsp + 0);               // 50016 ints
    int*    offsets   = (int*)(wsp + 200064);          // 50032 ints (uses 50001)
    int*    blocksums = (int*)(wsp + 400192);          // 64 ints
    ushort* rank      = (ushort*)(wsp + 400448);       // 800000 ushorts
    ushort* sorted    = (ushort*)(wsp + 2000448);      // 800016 ushorts
    ushort* x_bf      = (ushort*)(wsp + 3600480);      // 6,400,000 ushorts
    ushort* agg_bf    = (ushort*)(wsp + 16400480);     // 6,400,000 ushorts
    ushort* Btf       = (ushort*)(wsp + 29200480);     // 32768 ushorts
    // total = 29,266,016 bytes

    hipMemsetAsync(deg, 0, 50016 * sizeof(int), stream);
    conv_hist_kernel<<<(N_NODES * D / 4 + 255) / 256, 256, 0, stream>>>(
        x, Wl, Wr, dst, deg, rank, x_bf, Btf, E);
    scanA_kernel<<<SCAN_NBLK, 256, 0, stream>>>(deg, offsets, blocksums);
    scanBC_kernel<<<SCAN_NBLK, 256, 0, stream>>>(offsets, blocksums, E);
    scatter_kernel<<<(E + 255) / 256, 256, 0, stream>>>(src, dst, offsets, rank, sorted, E);
    aggregate_bf<<<(N_NODES + 15) / 16, 256, 0, stream>>>(x_bf, sorted, offsets, agg_bf);
    gemm_direct<<<(N_NODES + 63) / 64, 256, 0, stream>>>(agg_bf, x_bf, Btf, b, out);
}

// Round 7
// 113.561 us; speedup vs baseline: 1.2313x; 1.0516x over previous
//
#include <hip/hip_runtime.h>

#define N_NODES 50000
#define D 128
#define SCAN_NBLK 49   // ceil(50000/1024)

typedef short bf16x8 __attribute__((ext_vector_type(8)));
typedef float f32x4 __attribute__((ext_vector_type(4)));
typedef float f32x2 __attribute__((ext_vector_type(2)));

__device__ __forceinline__ ushort f2bf(float f) {
    uint u = __float_as_uint(f);
    u += 0x7FFF + ((u >> 16) & 1);     // round-to-nearest-even
    return (ushort)(u >> 16);
}

// unpack 16 fp8 (int4) and accumulate into a[0..16)
__device__ __forceinline__ void addrow_fp8(int4 q, float* a) {
    f32x2 p;
    p = __builtin_amdgcn_cvt_pk_f32_fp8(q.x, false); a[0]  += p.x; a[1]  += p.y;
    p = __builtin_amdgcn_cvt_pk_f32_fp8(q.x, true);  a[2]  += p.x; a[3]  += p.y;
    p = __builtin_amdgcn_cvt_pk_f32_fp8(q.y, false); a[4]  += p.x; a[5]  += p.y;
    p = __builtin_amdgcn_cvt_pk_f32_fp8(q.y, true);  a[6]  += p.x; a[7]  += p.y;
    p = __builtin_amdgcn_cvt_pk_f32_fp8(q.z, false); a[8]  += p.x; a[9]  += p.y;
    p = __builtin_amdgcn_cvt_pk_f32_fp8(q.z, true);  a[10] += p.x; a[11] += p.y;
    p = __builtin_amdgcn_cvt_pk_f32_fp8(q.w, false); a[12] += p.x; a[13] += p.y;
    p = __builtin_amdgcn_cvt_pk_f32_fp8(q.w, true);  a[14] += p.x; a[15] += p.y;
}

// ====== convert: x->bf16 + x->fp8 + fragment-major B build (pure BW) ========
__global__ __launch_bounds__(256) void convert_kernel(const float* __restrict__ x,
                                                      const float* __restrict__ Wl,
                                                      const float* __restrict__ Wr,
                                                      ushort* __restrict__ x_bf,
                                                      int* __restrict__ x_fp8,
                                                      ushort* __restrict__ Btf) {
    const int i = blockIdx.x * 256 + threadIdx.x;
    if (i < (N_NODES * D) / 4) {
        float4 v = ((const float4*)x)[i];
        ushort4 o;
        o.x = f2bf(v.x); o.y = f2bf(v.y); o.z = f2bf(v.z); o.w = f2bf(v.w);
        ((ushort4*)x_bf)[i] = o;
        int p = __builtin_amdgcn_cvt_pk_fp8_f32(v.x, v.y, 0, false);
        p = __builtin_amdgcn_cvt_pk_fp8_f32(v.z, v.w, p, true);
        x_fp8[i] = p;
    }
    // fragment-major B: Btf[((ks*8+nf)*64 + l)*8 + j] = W[k][col]
    if (i < 32768) {
        int j  = i & 7;
        int l  = (i >> 3) & 63;
        int nf = (i >> 9) & 7;
        int ks = (i >> 12) & 7;
        int lr = l & 15, kb = l >> 4;
        int col  = nf * 16 + lr;
        int kloc = (ks & 3) * 32 + kb * 8 + j;
        const float* W = (ks < 4) ? Wl : Wr;
        Btf[i] = f2bf(W[kloc * D + col]);
    }
}

// ---------------- histogram + per-edge rank (atomic-bound, standalone) ------
__global__ void hist_rank_kernel(const int* __restrict__ dst, int* __restrict__ deg,
                                 ushort* __restrict__ rank, int E) {
    int e = blockIdx.x * 256 + threadIdx.x;
    if (e < E) rank[e] = (ushort)atomicAdd(&deg[dst[e]], 1);
}

// ---------------- scan A: per-1024-chunk local exclusive scan ---------------
__global__ __launch_bounds__(256) void scanA_kernel(const int* __restrict__ deg,
                                                    int* __restrict__ offsets,
                                                    int* __restrict__ blocksums) {
    __shared__ int wsums[4];
    __shared__ int wbase[4];
    const int t = threadIdx.x;
    const int lane = t & 63;
    const int wid = t >> 6;
    const int base = blockIdx.x * 1024 + t * 4;

    int v0 = 0, v1 = 0, v2 = 0, v3 = 0;
    if (base + 3 < N_NODES) {
        int4 q = *(const int4*)&deg[base];
        v0 = q.x; v1 = q.y; v2 = q.z; v3 = q.w;
    } else {
        if (base + 0 < N_NODES) v0 = deg[base + 0];
        if (base + 1 < N_NODES) v1 = deg[base + 1];
        if (base + 2 < N_NODES) v2 = deg[base + 2];
        if (base + 3 < N_NODES) v3 = deg[base + 3];
    }
    int tsum = v0 + v1 + v2 + v3;

    int sc = tsum;
    #pragma unroll
    for (int off = 1; off < 64; off <<= 1) {
        int u = __shfl_up(sc, off);
        if (lane >= off) sc += u;
    }
    if (lane == 63) wsums[wid] = sc;
    __syncthreads();
    if (t == 0) {
        int c = 0;
        #pragma unroll
        for (int w = 0; w < 4; ++w) { wbase[w] = c; c += wsums[w]; }
    }
    __syncthreads();

    int excl = wbase[wid] + sc - tsum;
    int o0 = excl, o1 = o0 + v0, o2 = o1 + v1, o3 = o2 + v2;
    if (base + 3 < N_NODES) {
        *(int4*)&offsets[base] = make_int4(o0, o1, o2, o3);
    } else {
        if (base + 0 < N_NODES) offsets[base + 0] = o0;
        if (base + 1 < N_NODES) offsets[base + 1] = o1;
        if (base + 2 < N_NODES) offsets[base + 2] = o2;
        if (base + 3 < N_NODES) offsets[base + 3] = o3;
    }
    if (t == 255) blocksums[blockIdx.x] = excl + tsum;
}

// ---------------- scan BC: add block prefix (each block recomputes it) ------
__global__ __launch_bounds__(256) void scanBC_kernel(int* __restrict__ offsets,
                                                     const int* __restrict__ blocksums,
                                                     int E) {
    __shared__ int sbase;
    const int t = threadIdx.x;
    const int b = blockIdx.x;
    if (t < 64) {
        int v = (t < b) ? blocksums[t] : 0;
        #pragma unroll
        for (int off = 32; off > 0; off >>= 1) v += __shfl_down(v, off);
        if (t == 0) sbase = v;
    }
    __syncthreads();
    const int add = sbase;
    int base = b * 1024 + t * 4;
    if (base + 3 < N_NODES) {
        int4 q = *(int4*)&offsets[base];
        q.x += add; q.y += add; q.z += add; q.w += add;
        *(int4*)&offsets[base] = q;
    } else {
        if (base + 0 < N_NODES) offsets[base + 0] += add;
        if (base + 1 < N_NODES) offsets[base + 1] += add;
        if (base + 2 < N_NODES) offsets[base + 2] += add;
    }
    if (b == SCAN_NBLK - 1 && t == 0) offsets[N_NODES] = E;
}

// ---------------- scatter edges into CSR order (no atomics, ushort) --------
__global__ void scatter_kernel(const int* __restrict__ src, const int* __restrict__ dst,
                               const int* __restrict__ offsets, const ushort* __restrict__ rank,
                               ushort* __restrict__ sorted_src, int E) {
    int e = blockIdx.x * 256 + threadIdx.x;
    if (e < E) {
        int d = dst[e];
        sorted_src[offsets[d] + (int)rank[e]] = (ushort)src[e];
    }
}

// ---------------- per-node mean aggregation (fp8 gather) -> bf16 -----------
// 8 lanes per node (int4 = 16 fp8 each), 32 nodes per 256-thread block
__global__ __launch_bounds__(256) void aggregate_fp8(const int* __restrict__ x_fp8,
                                                     const ushort* __restrict__ sorted_src,
                                                     const int* __restrict__ offsets,
                                                     ushort* __restrict__ agg_bf) {
    const int g = threadIdx.x >> 3;          // node slot 0..31
    const int j = threadIdx.x & 7;           // feature chunk: elems j*16..j*16+15
    const int node = blockIdx.x * 32 + g;
    if (node >= N_NODES) return;
    const int s = offsets[node];
    const int e = offsets[node + 1];

    float a[16];
    #pragma unroll
    for (int k = 0; k < 16; ++k) a[k] = 0.0f;

    const int4* xq = (const int4*)x_fp8;     // one int4 = 16 fp8; row = 8 int4s
    int p = s;
    for (; p + 4 <= e; p += 4) {
        int s0 = sorted_src[p + 0];
        int s1 = sorted_src[p + 1];
        int s2 = sorted_src[p + 2];
        int s3 = sorted_src[p + 3];
        int4 q0 = xq[s0 * 8 + j];
        int4 q1 = xq[s1 * 8 + j];
        int4 q2 = xq[s2 * 8 + j];
        int4 q3 = xq[s3 * 8 + j];
        addrow_fp8(q0, a); addrow_fp8(q1, a); addrow_fp8(q2, a); addrow_fp8(q3, a);
    }
    for (; p < e; ++p) {
        int s0 = sorted_src[p];
        int4 q0 = xq[s0 * 8 + j];
        addrow_fp8(q0, a);
    }
    const int dcnt = e - s;
    const float scale = (dcnt > 0) ? (1.0f / (float)dcnt) : 0.0f;
    ushort tmp[16];
    #pragma unroll
    for (int k = 0; k < 16; ++k) tmp[k] = f2bf(a[k] * scale);
    *(int4*)&agg_bf[node * D + j * 16] = ((int4*)tmp)[0];
    *(int4*)&agg_bf[node * D + j * 16 + 8] = ((int4*)tmp)[1];
}

// ---------------- GEMM, 0 LDS, 0 barriers: out=relu([agg|x]@[Wl;Wr]+b) -----
__global__ __launch_bounds__(256) void gemm_direct(const ushort* __restrict__ agg_bf,
                                                   const ushort* __restrict__ x_bf,
                                                   const ushort* __restrict__ Btf,
                                                   const float* __restrict__ bias,
                                                   float* __restrict__ out) {
    const int t = threadIdx.x;
    const int w = t >> 6;
    const int l = t & 63;
    const int lr = l & 15;
    const int kb = l >> 4;
    const int n0 = blockIdx.x * 64;

    int r = n0 + w * 16 + lr;
    if (r >= N_NODES) r = N_NODES - 1;

    f32x4 acc[8] = {};

    #pragma unroll
    for (int ks = 0; ks < 8; ++ks) {
        bf16x8 af = (ks < 4)
            ? *(const bf16x8*)&agg_bf[r * D + ks * 32 + kb * 8]
            : *(const bf16x8*)&x_bf[r * D + (ks - 4) * 32 + kb * 8];
        const ushort* bp = Btf + (size_t)(ks * 8 * 64 + l) * 8;
        #pragma unroll
        for (int nf = 0; nf < 8; ++nf) {
            bf16x8 bfr = *(const bf16x8*)&bp[nf * 64 * 8];
            acc[nf] = __builtin_amdgcn_mfma_f32_16x16x32_bf16(af, bfr, acc[nf], 0, 0, 0);
        }
    }

    // C/D layout: col = lane&15, row = (lane>>4)*4 + i
    #pragma unroll
    for (int nf = 0; nf < 8; ++nf) {
        const int col = nf * 16 + lr;
        const float bb = bias[col];
        #pragma unroll
        for (int i = 0; i < 4; ++i) {
            int row = n0 + w * 16 + kb * 4 + i;
            if (row < N_NODES)
                out[row * D + col] = fmaxf(acc[nf][i] + bb, 0.0f);
        }
    }
}

// ============================================================================
extern "C" void kernel_launch(void* const* d_in, const int* in_sizes, int n_in,
                              void* d_out, int out_size, void* d_ws, size_t ws_size,
                              hipStream_t stream) {
    const float* x  = (const float*)d_in[0];
    const int*   ei = (const int*)d_in[1];
    const float* Wl = (const float*)d_in[2];
    const float* Wr = (const float*)d_in[3];
    const float* b  = (const float*)d_in[4];
    float* out = (float*)d_out;

    const int E = in_sizes[1] / 2;
    const int* src = ei;
    const int* dst = ei + E;

    // workspace layout (16B-aligned sections)
    char* wsp = (char*)d_ws;
    int*    deg       = (int*)(wsp + 0);               // 50016 ints
    int*    offsets   = (int*)(wsp + 200064);          // 50032 ints (uses 50001)
    int*    blocksums = (int*)(wsp + 400192);          // 64 ints
    ushort* rank      = (ushort*)(wsp + 400448);       // 800000 ushorts
    ushort* sorted    = (ushort*)(wsp + 2000448);      // 800016 ushorts
    ushort* x_bf      = (ushort*)(wsp + 3600480);      // 6,400,000 ushorts
    ushort* agg_bf    = (ushort*)(wsp + 16400480);     // 6,400,000 ushorts
    int*    x_fp8     = (int*)(wsp + 29200480);        // 1,600,000 ints (6.4MB)
    ushort* Btf       = (ushort*)(wsp + 35600480);     // 32768 ushorts
    // total = 35,666,016 bytes

    hipMemsetAsync(deg, 0, 50016 * sizeof(int), stream);
    hist_rank_kernel<<<(E + 255) / 256, 256, 0, stream>>>(dst, deg, rank, E);
    convert_kernel<<<(N_NODES * D / 4 + 255) / 256, 256, 0, stream>>>(
        x, Wl, Wr, x_bf, x_fp8, Btf);
    scanA_kernel<<<SCAN_NBLK, 256, 0, stream>>>(deg, offsets, blocksums);
    scanBC_kernel<<<SCAN_NBLK, 256, 0, stream>>>(offsets, blocksums, E);
    scatter_kernel<<<(E + 255) / 256, 256, 0, stream>>>(src, dst, offsets, rank, sorted, E);
    aggregate_fp8<<<(N_NODES + 31) / 32, 256, 0, stream>>>(x_fp8, sorted, offsets, agg_bf);
    gemm_direct<<<(N_NODES + 63) / 64, 256, 0, stream>>>(agg_bf, x_bf, Btf, b, out);
}

// Round 8
// 110.628 us; speedup vs baseline: 1.2639x; 1.0265x over previous
//
#include <hip/hip_runtime.h>

#define N_NODES 50000
#define D 128
#define NC 128                 // edge chunks (= countA/scatterC grid)
#define SCANB 196              // scanAB blocks (196*256 = 50176 >= N)

typedef short bf16x8 __attribute__((ext_vector_type(8)));
typedef float f32x4 __attribute__((ext_vector_type(4)));
typedef float f32x2 __attribute__((ext_vector_type(2)));

__device__ __forceinline__ ushort f2bf(float f) {
    uint u = __float_as_uint(f);
    u += 0x7FFF + ((u >> 16) & 1);     // round-to-nearest-even
    return (ushort)(u >> 16);
}

// unpack 16 fp8 (int4) and accumulate into a[0..16)
__device__ __forceinline__ void addrow_fp8(int4 q, float* a) {
    f32x2 p;
    p = __builtin_amdgcn_cvt_pk_f32_fp8(q.x, false); a[0]  += p.x; a[1]  += p.y;
    p = __builtin_amdgcn_cvt_pk_f32_fp8(q.x, true);  a[2]  += p.x; a[3]  += p.y;
    p = __builtin_amdgcn_cvt_pk_f32_fp8(q.y, false); a[4]  += p.x; a[5]  += p.y;
    p = __builtin_amdgcn_cvt_pk_f32_fp8(q.y, true);  a[6]  += p.x; a[7]  += p.y;
    p = __builtin_amdgcn_cvt_pk_f32_fp8(q.z, false); a[8]  += p.x; a[9]  += p.y;
    p = __builtin_amdgcn_cvt_pk_f32_fp8(q.z, true);  a[10] += p.x; a[11] += p.y;
    p = __builtin_amdgcn_cvt_pk_f32_fp8(q.w, false); a[12] += p.x; a[13] += p.y;
    p = __builtin_amdgcn_cvt_pk_f32_fp8(q.w, true);  a[14] += p.x; a[15] += p.y;
}

// ====== convert: x->bf16 + x->fp8 + fragment-major B build (pure BW) ========
__global__ __launch_bounds__(256) void convert_kernel(const float* __restrict__ x,
                                                      const float* __restrict__ Wl,
                                                      const float* __restrict__ Wr,
                                                      ushort* __restrict__ x_bf,
                                                      int* __restrict__ x_fp8,
                                                      ushort* __restrict__ Btf) {
    const int i = blockIdx.x * 256 + threadIdx.x;
    if (i < (N_NODES * D) / 4) {
        float4 v = ((const float4*)x)[i];
        ushort4 o;
        o.x = f2bf(v.x); o.y = f2bf(v.y); o.z = f2bf(v.z); o.w = f2bf(v.w);
        ((ushort4*)x_bf)[i] = o;
        int p = __builtin_amdgcn_cvt_pk_fp8_f32(v.x, v.y, 0, false);
        p = __builtin_amdgcn_cvt_pk_fp8_f32(v.z, v.w, p, true);
        x_fp8[i] = p;
    }
    // fragment-major B: Btf[((ks*8+nf)*64 + l)*8 + j] = W[k][col]
    if (i < 32768) {
        int j  = i & 7;
        int l  = (i >> 3) & 63;
        int nf = (i >> 9) & 7;
        int ks = (i >> 12) & 7;
        int lr = l & 15, kb = l >> 4;
        int col  = nf * 16 + lr;
        int kloc = (ks & 3) * 32 + kb * 8 + j;
        const float* W = (ks < 4) ? Wl : Wr;
        Btf[i] = f2bf(W[kloc * D + col]);
    }
}

// ====== pass A: per-chunk LDS histogram (packed 2x ushort per uint) =========
// block b counts dst occurrences of its edge chunk into partial[b][0..N)
__global__ __launch_bounds__(256) void countA_kernel(const int* __restrict__ dst,
                                                     ushort* __restrict__ partial,
                                                     int E, int chunk) {
    __shared__ uint cnt[N_NODES / 2];     // 25000 uints = 100 KB
    const int t = threadIdx.x;
    const int b = blockIdx.x;
    for (int k = t; k < N_NODES / 2; k += 256) cnt[k] = 0;
    __syncthreads();
    const int e0 = b * chunk;
    const int e1 = min(E, e0 + chunk);
    for (int e = e0 + t; e < e1; e += 256) {
        int d = dst[e];
        atomicAdd(&cnt[d >> 1], 1u << ((d & 1) << 4));
    }
    __syncthreads();
    uint* pu = (uint*)(partial + (size_t)b * N_NODES);
    for (int k = t; k < N_NODES / 2; k += 256) pu[k] = cnt[k];
}

// ====== pass B: per-node chunk-prefix + degree + block-local exclusive scan =
__global__ __launch_bounds__(256) void scanAB_kernel(const ushort* __restrict__ partial,
                                                     ushort* __restrict__ cumbase,
                                                     int* __restrict__ offsets,
                                                     int* __restrict__ blocksums) {
    __shared__ int wsums[4];
    __shared__ int wbase[4];
    const int t = threadIdx.x;
    const int lane = t & 63;
    const int wid = t >> 6;
    const int n = blockIdx.x * 256 + t;

    int s = 0;
    if (n < N_NODES) {
        #pragma unroll 4
        for (int c = 0; c < NC; ++c) {
            int v = (int)partial[(size_t)c * N_NODES + n];
            cumbase[(size_t)c * N_NODES + n] = (ushort)s;
            s += v;
        }
    }
    // block exclusive scan of s (256 threads = 4 waves)
    int sc = s;
    #pragma unroll
    for (int off = 1; off < 64; off <<= 1) {
        int u = __shfl_up(sc, off);
        if (lane >= off) sc += u;
    }
    if (lane == 63) wsums[wid] = sc;
    __syncthreads();
    if (t == 0) {
        int c = 0;
        #pragma unroll
        for (int w = 0; w < 4; ++w) { int tmp = wsums[w]; wbase[w] = c; c += tmp; }
        blocksums[blockIdx.x] = c;
    }
    __syncthreads();
    if (n < N_NODES) offsets[n] = wbase[wid] + sc - s;
}

// ====== pass BC: add cross-block prefix of blocksums ========================
__global__ __launch_bounds__(256) void scanBC2_kernel(int* __restrict__ offsets,
                                                      const int* __restrict__ blocksums,
                                                      int E) {
    __shared__ int ws2[4];
    __shared__ int sbase;
    const int t = threadIdx.x;
    const int lane = t & 63;
    const int wid = t >> 6;
    const int b = blockIdx.x;
    int v = (t < b) ? blocksums[t] : 0;    // b <= SCANB-1 < 256
    #pragma unroll
    for (int off = 32; off > 0; off >>= 1) v += __shfl_down(v, off);
    if (lane == 0) ws2[wid] = v;
    __syncthreads();
    if (t == 0) sbase = ws2[0] + ws2[1] + ws2[2] + ws2[3];
    __syncthreads();
    const int n = b * 256 + t;
    if (n < N_NODES) offsets[n] += sbase;
    if (b == SCANB - 1 && t == 0) offsets[N_NODES] = E;
}

// ====== pass C: scatter into CSR (LDS ranks, no device atomics) =============
__global__ __launch_bounds__(256) void scatterC_kernel(const int* __restrict__ src,
                                                       const int* __restrict__ dst,
                                                       const int* __restrict__ offsets,
                                                       const ushort* __restrict__ cumbase,
                                                       ushort* __restrict__ sorted_src,
                                                       int E, int chunk) {
    __shared__ uint cnt[N_NODES / 2];     // 100 KB
    const int t = threadIdx.x;
    const int b = blockIdx.x;
    for (int k = t; k < N_NODES / 2; k += 256) cnt[k] = 0;
    __syncthreads();
    const ushort* cb = cumbase + (size_t)b * N_NODES;   // this chunk's slice (100KB, L2-hot)
    const int e0 = b * chunk;
    const int e1 = min(E, e0 + chunk);
    for (int e = e0 + t; e < e1; e += 256) {
        int d = dst[e];
        uint prev = atomicAdd(&cnt[d >> 1], 1u << ((d & 1) << 4));
        int lrank = (int)((prev >> ((d & 1) << 4)) & 0xFFFFu);
        int pos = offsets[d] + (int)cb[d] + lrank;
        sorted_src[pos] = (ushort)src[e];
    }
}

// ---------------- per-node mean aggregation (fp8 gather) -> bf16 -----------
// 8 lanes per node (int4 = 16 fp8 each), 32 nodes per 256-thread block
__global__ __launch_bounds__(256) void aggregate_fp8(const int* __restrict__ x_fp8,
                                                     const ushort* __restrict__ sorted_src,
                                                     const int* __restrict__ offsets,
                                                     ushort* __restrict__ agg_bf) {
    const int g = threadIdx.x >> 3;          // node slot 0..31
    const int j = threadIdx.x & 7;           // feature chunk: elems j*16..j*16+15
    const int node = blockIdx.x * 32 + g;
    if (node >= N_NODES) return;
    const int s = offsets[node];
    const int e = offsets[node + 1];

    float a[16];
    #pragma unroll
    for (int k = 0; k < 16; ++k) a[k] = 0.0f;

    const int4* xq = (const int4*)x_fp8;     // one int4 = 16 fp8; row = 8 int4s
    int p = s;
    for (; p + 4 <= e; p += 4) {
        int s0 = sorted_src[p + 0];
        int s1 = sorted_src[p + 1];
        int s2 = sorted_src[p + 2];
        int s3 = sorted_src[p + 3];
        int4 q0 = xq[s0 * 8 + j];
        int4 q1 = xq[s1 * 8 + j];
        int4 q2 = xq[s2 * 8 + j];
        int4 q3 = xq[s3 * 8 + j];
        addrow_fp8(q0, a); addrow_fp8(q1, a); addrow_fp8(q2, a); addrow_fp8(q3, a);
    }
    for (; p < e; ++p) {
        int s0 = sorted_src[p];
        int4 q0 = xq[s0 * 8 + j];
        addrow_fp8(q0, a);
    }
    const int dcnt = e - s;
    const float scale = (dcnt > 0) ? (1.0f / (float)dcnt) : 0.0f;
    ushort tmp[16];
    #pragma unroll
    for (int k = 0; k < 16; ++k) tmp[k] = f2bf(a[k] * scale);
    *(int4*)&agg_bf[node * D + j * 16] = ((int4*)tmp)[0];
    *(int4*)&agg_bf[node * D + j * 16 + 8] = ((int4*)tmp)[1];
}

// ---------------- GEMM, 0 LDS, 0 barriers: out=relu([agg|x]@[Wl;Wr]+b) -----
__global__ __launch_bounds__(256) void gemm_direct(const ushort* __restrict__ agg_bf,
                                                   const ushort* __restrict__ x_bf,
                                                   const ushort* __restrict__ Btf,
                                                   const float* __restrict__ bias,
                                                   float* __restrict__ out) {
    const int t = threadIdx.x;
    const int w = t >> 6;
    const int l = t & 63;
    const int lr = l & 15;
    const int kb = l >> 4;
    const int n0 = blockIdx.x * 64;

    int r = n0 + w * 16 + lr;
    if (r >= N_NODES) r = N_NODES - 1;

    f32x4 acc[8] = {};

    #pragma unroll
    for (int ks = 0; ks < 8; ++ks) {
        bf16x8 af = (ks < 4)
            ? *(const bf16x8*)&agg_bf[r * D + ks * 32 + kb * 8]
            : *(const bf16x8*)&x_bf[r * D + (ks - 4) * 32 + kb * 8];
        const ushort* bp = Btf + (size_t)(ks * 8 * 64 + l) * 8;
        #pragma unroll
        for (int nf = 0; nf < 8; ++nf) {
            bf16x8 bfr = *(const bf16x8*)&bp[nf * 64 * 8];
            acc[nf] = __builtin_amdgcn_mfma_f32_16x16x32_bf16(af, bfr, acc[nf], 0, 0, 0);
        }
    }

    // C/D layout: col = lane&15, row = (lane>>4)*4 + i
    #pragma unroll
    for (int nf = 0; nf < 8; ++nf) {
        const int col = nf * 16 + lr;
        const float bb = bias[col];
        #pragma unroll
        for (int i = 0; i < 4; ++i) {
            int row = n0 + w * 16 + kb * 4 + i;
            if (row < N_NODES)
                out[row * D + col] = fmaxf(acc[nf][i] + bb, 0.0f);
        }
    }
}

// ============================================================================
extern "C" void kernel_launch(void* const* d_in, const int* in_sizes, int n_in,
                              void* d_out, int out_size, void* d_ws, size_t ws_size,
                              hipStream_t stream) {
    const float* x  = (const float*)d_in[0];
    const int*   ei = (const int*)d_in[1];
    const float* Wl = (const float*)d_in[2];
    const float* Wr = (const float*)d_in[3];
    const float* b  = (const float*)d_in[4];
    float* out = (float*)d_out;

    const int E = in_sizes[1] / 2;
    const int* src = ei;
    const int* dst = ei + E;
    const int chunk = (E + NC - 1) / NC;

    // workspace layout (16B-aligned sections)
    char* wsp = (char*)d_ws;
    int*    offsets   = (int*)(wsp + 0);               // 50032 ints (uses 50001)
    int*    blocksums = (int*)(wsp + 200192);          // 256 ints
    ushort* sorted    = (ushort*)(wsp + 201216);       // 800016 ushorts
    ushort* partial   = (ushort*)(wsp + 1801280);      // 128*50000 ushorts (12.8MB)
    ushort* cumbase   = (ushort*)(wsp + 14601280);     // 128*50000 ushorts (12.8MB)
    ushort* x_bf      = (ushort*)(wsp + 27401280);     // 6,400,000 ushorts
    ushort* agg_bf    = (ushort*)(wsp + 40201280);     // 6,400,000 ushorts
    int*    x_fp8     = (int*)(wsp + 53001280);        // 1,600,000 ints
    ushort* Btf       = (ushort*)(wsp + 59401280);     // 32768 ushorts
    // total = 59,466,816 bytes

    convert_kernel<<<(N_NODES * D / 4 + 255) / 256, 256, 0, stream>>>(
        x, Wl, Wr, x_bf, x_fp8, Btf);
    countA_kernel<<<NC, 256, 0, stream>>>(dst, partial, E, chunk);
    scanAB_kernel<<<SCANB, 256, 0, stream>>>(partial, cumbase, offsets, blocksums);
    scanBC2_kernel<<<SCANB, 256, 0, stream>>>(offsets, blocksums, E);
    scatterC_kernel<<<NC, 256, 0, stream>>>(src, dst, offsets, cumbase, sorted, E, chunk);
    aggregate_fp8<<<(N_NODES + 31) / 32, 256, 0, stream>>>(x_fp8, sorted, offsets, agg_bf);
    gemm_direct<<<(N_NODES + 63) / 64, 256, 0, stream>>>(agg_bf, x_bf, Btf, b, out);
}